// Round 5
// baseline (356.929 us; speedup 1.0000x reference)
//
#include <hip/hip_runtime.h>
#include <hip/hip_bf16.h>
#include <hip/hip_fp16.h>

#define NH 8
#define ED 128
#define NB 8
#define NN 1024

typedef __attribute__((ext_vector_type(8))) short s16x8;
typedef __attribute__((ext_vector_type(8))) __bf16 bf16x8_t;
typedef __attribute__((ext_vector_type(4))) float f32x4;

static __device__ __forceinline__ unsigned short f2bf(float f) {
    union { float f; unsigned u; } v; v.f = f;
    unsigned r = v.u + 0x7fffu + ((v.u >> 16) & 1u);
    return (unsigned short)(r >> 16);
}

static __device__ __forceinline__ f32x4 mfma16(s16x8 a, s16x8 b, f32x4 c) {
    return __builtin_amdgcn_mfma_f32_16x16x32_bf16(
        __builtin_bit_cast(bf16x8_t, a), __builtin_bit_cast(bf16x8_t, b), c, 0, 0, 0);
}

// async global->LDS, 16B per lane; LDS dest is wave-uniform base + lane*16
static __device__ __forceinline__ void gll16(const void* g, void* l) {
    __builtin_amdgcn_global_load_lds((const __attribute__((address_space(1))) void*)g,
                                     (__attribute__((address_space(3))) void*)l, 16, 0, 0);
}

// ---------- fused prep: cvt x -> bf16, transpose weights -> bf16, dist -> f16 ----------
__global__ __launch_bounds__(256) void prep_kernel(
    const float* __restrict__ x,
    const float* __restrict__ Wq, const float* __restrict__ Wk,
    const float* __restrict__ Wv, const float* __restrict__ Wo,
    const float* __restrict__ dist,
    unsigned short* __restrict__ xb,
    unsigned short* __restrict__ wqt, unsigned short* __restrict__ wkt,
    unsigned short* __restrict__ wvt, unsigned short* __restrict__ wot,
    __half* __restrict__ dist_h) {
    int bid = blockIdx.x, tid = threadIdx.x;
    if (bid < 1024) {
        int i = bid * 256 + tid;   // 4 f32 -> 4 bf16 per thread
        float4 v = ((const float4*)x)[i];
        unsigned long long pk = (unsigned long long)f2bf(v.x)
                              | ((unsigned long long)f2bf(v.y) << 16)
                              | ((unsigned long long)f2bf(v.z) << 32)
                              | ((unsigned long long)f2bf(v.w) << 48);
        ((unsigned long long*)xb)[i] = pk;
        return;
    }
    if (bid >= 3072) {
        int i = (bid - 3072) * 256 + tid;   // dist: 4 f32 -> 4 f16 per thread
        float4 v = ((const float4*)dist)[i];
        unsigned long long pk = (unsigned long long)__half_as_ushort(__float2half_rn(v.x))
                              | ((unsigned long long)__half_as_ushort(__float2half_rn(v.y)) << 16)
                              | ((unsigned long long)__half_as_ushort(__float2half_rn(v.z)) << 32)
                              | ((unsigned long long)__half_as_ushort(__float2half_rn(v.w)) << 48);
        ((unsigned long long*)dist_h)[i] = pk;
        return;
    }
    const float* in; unsigned short* outp; int rows_in, cols_in, i;
    if (bid < 1536)      { in = Wq; outp = wqt; rows_in = 128;  cols_in = 1024; i = (bid - 1024) * 256 + tid; }
    else if (bid < 2048) { in = Wk; outp = wkt; rows_in = 128;  cols_in = 1024; i = (bid - 1536) * 256 + tid; }
    else if (bid < 2560) { in = Wv; outp = wvt; rows_in = 128;  cols_in = 1024; i = (bid - 2048) * 256 + tid; }
    else                 { in = Wo; outp = wot; rows_in = 1024; cols_in = 128;  i = (bid - 2560) * 256 + tid; }
    int c = i / rows_in;
    int r = i - c * rows_in;
    outp[i] = f2bf(in[(size_t)r * cols_in + c]);
}

// ---------- QKV projection: writes q linear, k/v PRE-SWIZZLED 16KB tiles ----------
__global__ __launch_bounds__(256) void qkv_kernel(
    const unsigned short* __restrict__ xb,
    const unsigned short* __restrict__ wqt,
    const unsigned short* __restrict__ wkt,
    const unsigned short* __restrict__ wvt,
    const float* __restrict__ bq, const float* __restrict__ bk, const float* __restrict__ bv,
    unsigned short* __restrict__ q_ws,
    unsigned short* __restrict__ k_ws,
    unsigned short* __restrict__ v_ws) {
    int bid = blockIdx.x;
    int mt = bid / 24, c = bid % 24;
    int which = c >> 3;
    int c0 = (c & 7) * 128;
    int m0 = mt * 128;
    int tid = threadIdx.x;
    int w = tid >> 6, lane = tid & 63, g = lane >> 4, r15 = lane & 15;
    int wr = (w >> 1) * 64, wc = (w & 1) * 64;

    const unsigned short* wt = (which == 0) ? wqt : (which == 1) ? wkt : wvt;
    const float* bias = (which == 0) ? bq : (which == 1) ? bk : bv;

    const f32x4 fzero = {0.f, 0.f, 0.f, 0.f};
    f32x4 acc[4][4];
#pragma unroll
    for (int i = 0; i < 4; i++)
#pragma unroll
        for (int j = 0; j < 4; j++) acc[i][j] = fzero;

#pragma unroll
    for (int kf = 0; kf < 4; kf++) {
        s16x8 af[4], bfr[4];
#pragma unroll
        for (int mf = 0; mf < 4; mf++)
            af[mf] = *(const s16x8*)(xb + (size_t)(m0 + wr + mf * 16 + r15) * ED + kf * 32 + g * 8);
#pragma unroll
        for (int nf = 0; nf < 4; nf++)
            bfr[nf] = *(const s16x8*)(wt + (size_t)(c0 + wc + nf * 16 + r15) * ED + kf * 32 + g * 8);
#pragma unroll
        for (int mf = 0; mf < 4; mf++)
#pragma unroll
            for (int nf = 0; nf < 4; nf++)
                acc[mf][nf] = mfma16(af[mf], bfr[nf], acc[mf][nf]);
    }

    float scale = (which == 0) ? 0.08838834764831845f : 1.0f;   // 1/sqrt(128) for q only

#pragma unroll
    for (int nf = 0; nf < 4; nf++) {
        int col = c0 + wc + nf * 16 + r15;
        float bv_ = bias[col];
        int hh = col >> 7, e = col & 127;
#pragma unroll
        for (int mf = 0; mf < 4; mf++) {
#pragma unroll
            for (int rr = 0; rr < 4; rr++) {
                int row = m0 + wr + mf * 16 + g * 4 + rr;   // global token
                int bb = row >> 10, n = row & 1023;
                int bh = bb * NH + hh;
                float val = (acc[mf][nf][rr] + bv_) * scale;
                if (which == 0) {
                    q_ws[((size_t)bh * NN + n) * ED + e] = f2bf(val);
                } else if (which == 1) {
                    // K: per-64-key tile, byte = (row64*256 + e*2) ^ ((row64&7)<<4)
                    int ktl = n >> 6, row64 = n & 63;
                    int byt = (row64 * 256 + e * 2) ^ ((row64 & 7) << 4);
                    *(unsigned short*)((char*)k_ws + ((size_t)bh * 16 + ktl) * 16384 + byt) = f2bf(val);
                } else {
                    // V^T: per-64-key tile, byte = (e*128 + (n&63)*2) ^ ((e&7)<<4)
                    int ktl = n >> 6;
                    int byt = (e * 128 + (n & 63) * 2) ^ ((e & 7) << 4);
                    *(unsigned short*)((char*)v_ws + ((size_t)bh * 16 + ktl) * 16384 + byt) = f2bf(val);
                }
            }
        }
    }
}

// ---------- flash attention: 1-barrier full-dbuf pipeline, f16 dist ----------
__global__ __launch_bounds__(512, 4) void attn_kernel(
    const unsigned short* __restrict__ q_ws,
    const unsigned short* __restrict__ k_ws,
    const unsigned short* __restrict__ v_ws,
    const __half* __restrict__ dist_h,
    const float* __restrict__ mask,
    unsigned short* __restrict__ y_ws) {
    // XCD swizzle: all blocks on XCD x have b == x -> dist_h[b] (2MB) fully L2-resident
    int p = blockIdx.x;
    int xcd = p & 7, j = p >> 3;
    int bh = xcd * 8 + (j >> 3);
    int qt = j & 7;
    int b = xcd;
    int q0 = qt * 128;

    int tid = threadIdx.x;
    int w = tid >> 6, lane = tid & 63, g = lane >> 4, r15 = lane & 15;

    __shared__ __align__(16) unsigned short Kl[2][8192];   // 32 KB double-buffered
    __shared__ __align__(16) unsigned short Vt[2][8192];   // 32 KB double-buffered
    __shared__ __align__(16) unsigned short Pl[8][1024];   // 16 KB (wave-private)

    const char* kg = (const char*)k_ws + (size_t)bh * 16 * 16384;
    const char* vg = (const char*)v_ws + (size_t)bh * 16 * 16384;
    const float* mbase = mask + b * NN;
    const __half* drow = dist_h + (size_t)b * NN * NN + (size_t)(q0 + w * 16 + g * 4) * NN + r15;

    // Q fragments (registers)
    s16x8 qf[4];
    const unsigned short* qb = q_ws + ((size_t)bh * NN + q0 + w * 16 + r15) * ED;
#pragma unroll
    for (int kf = 0; kf < 4; kf++) qf[kf] = *(const s16x8*)(qb + kf * 32 + g * 8);

    const f32x4 fzero = {0.f, 0.f, 0.f, 0.f};
    f32x4 o[8];
#pragma unroll
    for (int i = 0; i < 8; i++) o[i] = fzero;
    float l_r[4] = {0.f, 0.f, 0.f, 0.f};

    int soff = w * 1024 + lane * 16;          // per-lane src byte offset within a staging half
    int doff = w * 1024;                      // wave-uniform LDS dest byte offset

    // prologue: tile 0 -> buffers [0]; dist row chunk 0 -> regs
#pragma unroll
    for (int it = 0; it < 2; ++it) {
        gll16(kg + it * 8192 + soff, (char*)&Kl[0][0] + it * 8192 + doff);
        gll16(vg + it * 8192 + soff, (char*)&Vt[0][0] + it * 8192 + doff);
    }
    float dvv[4][4];
#pragma unroll
    for (int nf = 0; nf < 4; nf++)
#pragma unroll
        for (int rr = 0; rr < 4; rr++)
            dvv[nf][rr] = __half2float(drow[(size_t)rr * NN + nf * 16]);

    for (int kt = 0; kt < 16; ++kt) {
        int cur = kt & 1;
        int k0 = kt * 64;
        __syncthreads();   // drains glls issued last iteration (full-iter slack)

        // issue next tile into [nxt] (in flight across the whole compute phase)
        if (kt < 15) {
            int nxt = cur ^ 1;
#pragma unroll
            for (int it = 0; it < 2; ++it) {
                gll16(kg + (size_t)(kt + 1) * 16384 + it * 8192 + soff, (char*)&Kl[nxt][0] + it * 8192 + doff);
                gll16(vg + (size_t)(kt + 1) * 16384 + it * 8192 + soff, (char*)&Vt[nxt][0] + it * 8192 + doff);
            }
        }

        // dist for NEXT iteration (L2-resident f16; full-iter slack)
        float dnx[4][4];
        if (kt < 15) {
#pragma unroll
            for (int nf = 0; nf < 4; nf++)
#pragma unroll
                for (int rr = 0; rr < 4; rr++)
                    dnx[nf][rr] = __half2float(drow[(size_t)rr * NN + k0 + 64 + nf * 16]);
        }
        float mkf[4];
#pragma unroll
        for (int nf = 0; nf < 4; nf++) mkf[nf] = mbase[k0 + nf * 16 + r15];

        // S = Q K^T  (D-layout: row=g*4+rr, col=nf*16+r15 = key)
        const char* kbuf = (const char*)&Kl[cur][0];
        f32x4 s[4];
#pragma unroll
        for (int nf = 0; nf < 4; nf++) s[nf] = fzero;
        __builtin_amdgcn_s_setprio(1);
#pragma unroll
        for (int kf = 0; kf < 4; kf++) {
#pragma unroll
            for (int nf = 0; nf < 4; nf++) {
                int key = nf * 16 + r15;
                int byt = (key * 256 + kf * 64 + g * 16) ^ ((key & 7) << 4);
                s16x8 kb = *(const s16x8*)(kbuf + byt);
                s[nf] = mfma16(qf[kf], kb, s[nf]);
            }
        }
        __builtin_amdgcn_s_setprio(0);

        // fixed-max softmax: p = exp(s + dist - 16) * mk; l accumulates lane-locally
#pragma unroll
        for (int nf = 0; nf < 4; nf++) {
#pragma unroll
            for (int rr = 0; rr < 4; rr++) {
                float pv = __expf(s[nf][rr] + dvv[nf][rr] - 16.0f) * mkf[nf];
                s[nf][rr] = pv;
                l_r[rr] += pv;
            }
        }

        // P (D-layout) -> wave-private LDS (bf16), swizzled; no barrier needed
        unsigned short* pw = &Pl[w][0];
#pragma unroll
        for (int nf = 0; nf < 4; nf++) {
#pragma unroll
            for (int rr = 0; rr < 4; rr++) {
                int row = g * 4 + rr;
                int key = nf * 16 + r15;
                int byt = (row * 128 + key * 2) ^ ((row & 7) << 4);
                *(unsigned short*)((char*)pw + byt) = f2bf(s[nf][rr]);
            }
        }

        // O += P V  (Vt[cur] landed a full iteration ago; P ordered by lgkmcnt)
        const char* vbuf = (const char*)&Vt[cur][0];
        __builtin_amdgcn_s_setprio(1);
#pragma unroll
        for (int kf2 = 0; kf2 < 2; kf2++) {
            int ba = (r15 * 128 + (kf2 * 32 + g * 8) * 2) ^ ((r15 & 7) << 4);
            s16x8 pa = *(const s16x8*)((const char*)pw + ba);
#pragma unroll
            for (int nf = 0; nf < 8; nf++) {
                int e = nf * 16 + r15;
                int bb2 = (e * 128 + (kf2 * 32 + g * 8) * 2) ^ ((e & 7) << 4);
                s16x8 vb = *(const s16x8*)(vbuf + bb2);
                o[nf] = mfma16(pa, vb, o[nf]);
            }
        }
        __builtin_amdgcn_s_setprio(0);

#pragma unroll
        for (int nf = 0; nf < 4; nf++)
#pragma unroll
            for (int rr = 0; rr < 4; rr++)
                dvv[nf][rr] = dnx[nf][rr];
    }

    // epilogue: reduce l across the 16 key-lanes (once), normalize, write y
#pragma unroll
    for (int rr = 0; rr < 4; rr++) {
        float ps = l_r[rr];
        ps += __shfl_xor(ps, 1, 64);
        ps += __shfl_xor(ps, 2, 64);
        ps += __shfl_xor(ps, 4, 64);
        ps += __shfl_xor(ps, 8, 64);
        float inv = (ps > 0.f) ? 1.0f / ps : 0.f;
        int row_g = q0 + w * 16 + g * 4 + rr;
        size_t base = ((size_t)b * NN + row_g) * (NH * ED) + (bh & 7) * ED;
#pragma unroll
        for (int nf = 0; nf < 8; nf++)
            y_ws[base + nf * 16 + r15] = f2bf(o[nf][rr] * inv);
    }
}

// ---------- output projection: [8192,1024] @ [1024,128] + bo, * mask ----------
__global__ __launch_bounds__(256) void oproj_kernel(
    const unsigned short* __restrict__ y_ws,
    const unsigned short* __restrict__ wot,
    const float* __restrict__ bo,
    const float* __restrict__ mask,
    float* __restrict__ outp) {
    int bid = blockIdx.x;
    int mt = bid >> 1, nt = bid & 1;
    int m0 = mt * 64, c0 = nt * 64;
    int tid = threadIdx.x;
    int w = tid >> 6, lane = tid & 63, g = lane >> 4, r15 = lane & 15;

    const f32x4 fzero = {0.f, 0.f, 0.f, 0.f};
    f32x4 acc[4];
#pragma unroll
    for (int i = 0; i < 4; i++) acc[i] = fzero;

    const unsigned short* arow = y_ws + (size_t)(m0 + w * 16 + r15) * (NH * ED);
    for (int kt = 0; kt < 32; ++kt) {
        s16x8 af = *(const s16x8*)(arow + kt * 32 + g * 8);
#pragma unroll
        for (int nf = 0; nf < 4; nf++) {
            s16x8 bfr = *(const s16x8*)(wot + (size_t)(c0 + nf * 16 + r15) * (NH * ED) + kt * 32 + g * 8);
            acc[nf] = mfma16(af, bfr, acc[nf]);
        }
    }
#pragma unroll
    for (int nf = 0; nf < 4; nf++) {
        int col = c0 + nf * 16 + r15;
        float bias = bo[col];
#pragma unroll
        for (int rr = 0; rr < 4; rr++) {
            int token = m0 + w * 16 + g * 4 + rr;   // flat b*1024+n
            outp[(size_t)token * ED + col] = (acc[nf][rr] + bias) * mask[token];
        }
    }
}

extern "C" void kernel_launch(void* const* d_in, const int* in_sizes, int n_in,
                              void* d_out, int out_size, void* d_ws, size_t ws_size,
                              hipStream_t stream) {
    const float* x    = (const float*)d_in[0];
    const float* dist = (const float*)d_in[1];
    const float* mask = (const float*)d_in[2];
    const float* Wq   = (const float*)d_in[3];
    const float* bq   = (const float*)d_in[4];
    const float* Wk   = (const float*)d_in[5];
    const float* bk   = (const float*)d_in[6];
    const float* Wv   = (const float*)d_in[7];
    const float* bv   = (const float*)d_in[8];
    const float* Wo   = (const float*)d_in[9];
    const float* bo   = (const float*)d_in[10];
    float* outp = (float*)d_out;

    char* ws = (char*)d_ws;
    unsigned short* xb   = (unsigned short*)(ws);                              // 2 MB
    unsigned short* wqt  = (unsigned short*)(ws + (2u << 20));                 // 256 KB
    unsigned short* wkt  = (unsigned short*)(ws + (2u << 20) + (256u << 10));
    unsigned short* wvt  = (unsigned short*)(ws + (2u << 20) + (512u << 10));
    unsigned short* wot  = (unsigned short*)(ws + (2u << 20) + (768u << 10));
    unsigned short* q_ws = (unsigned short*)(ws + (3u << 20));                 // 16 MB
    unsigned short* k_ws = (unsigned short*)(ws + (19u << 20));                // 16 MB (pre-swizzled tiles)
    unsigned short* v_ws = (unsigned short*)(ws + (35u << 20));                // 16 MB (pre-swizzled V^T tiles)
    unsigned short* y_ws = (unsigned short*)(ws + (51u << 20));                // 16 MB
    __half*         dist_h = (__half*)(ws + (67u << 20));                      // 16.78 MB f16 dist

    prep_kernel<<<11264, 256, 0, stream>>>(x, Wq, Wk, Wv, Wo, dist, xb, wqt, wkt, wvt, wot, dist_h);
    qkv_kernel<<<1536, 256, 0, stream>>>(xb, wqt, wkt, wvt, bq, bk, bv, q_ws, k_ws, v_ws);
    attn_kernel<<<512, 512, 0, stream>>>(q_ws, k_ws, v_ws, dist_h, mask, y_ws);
    oproj_kernel<<<256, 256, 0, stream>>>(y_ws, wot, bo, mask, outp);
}

// Round 6
// 154.749 us; speedup vs baseline: 2.3065x; 2.3065x over previous
//
#include <hip/hip_runtime.h>
#include <hip/hip_bf16.h>

#define NH 8
#define ED 128
#define NB 8
#define NN 1024

typedef __attribute__((ext_vector_type(8))) short s16x8;
typedef __attribute__((ext_vector_type(8))) __bf16 bf16x8_t;
typedef __attribute__((ext_vector_type(4))) float f32x4;

static __device__ __forceinline__ unsigned short f2bf(float f) {
    union { float f; unsigned u; } v; v.f = f;
    unsigned r = v.u + 0x7fffu + ((v.u >> 16) & 1u);
    return (unsigned short)(r >> 16);
}

static __device__ __forceinline__ f32x4 mfma16(s16x8 a, s16x8 b, f32x4 c) {
    return __builtin_amdgcn_mfma_f32_16x16x32_bf16(
        __builtin_bit_cast(bf16x8_t, a), __builtin_bit_cast(bf16x8_t, b), c, 0, 0, 0);
}

// ---------- fused prep: cvt x -> bf16, transpose 4 weight mats -> bf16 ----------
__global__ __launch_bounds__(256) void prep_kernel(
    const float* __restrict__ x,
    const float* __restrict__ Wq, const float* __restrict__ Wk,
    const float* __restrict__ Wv, const float* __restrict__ Wo,
    unsigned short* __restrict__ xb,
    unsigned short* __restrict__ wqt, unsigned short* __restrict__ wkt,
    unsigned short* __restrict__ wvt, unsigned short* __restrict__ wot) {
    int bid = blockIdx.x, tid = threadIdx.x;
    if (bid < 1024) {
        int i = bid * 256 + tid;   // 4 f32 -> 4 bf16 per thread
        float4 v = ((const float4*)x)[i];
        unsigned long long pk = (unsigned long long)f2bf(v.x)
                              | ((unsigned long long)f2bf(v.y) << 16)
                              | ((unsigned long long)f2bf(v.z) << 32)
                              | ((unsigned long long)f2bf(v.w) << 48);
        ((unsigned long long*)xb)[i] = pk;
        return;
    }
    const float* in; unsigned short* outp; int rows_in, cols_in, i;
    if (bid < 1536)      { in = Wq; outp = wqt; rows_in = 128;  cols_in = 1024; i = (bid - 1024) * 256 + tid; }
    else if (bid < 2048) { in = Wk; outp = wkt; rows_in = 128;  cols_in = 1024; i = (bid - 1536) * 256 + tid; }
    else if (bid < 2560) { in = Wv; outp = wvt; rows_in = 128;  cols_in = 1024; i = (bid - 2048) * 256 + tid; }
    else                 { in = Wo; outp = wot; rows_in = 1024; cols_in = 128;  i = (bid - 2560) * 256 + tid; }
    int c = i / rows_in;
    int r = i - c * rows_in;
    outp[i] = f2bf(in[(size_t)r * cols_in + c]);
}

// ---------- QKV projection: q/k linear [bh][n][e], v transposed [bh][e][n] ----------
__global__ __launch_bounds__(256) void qkv_kernel(
    const unsigned short* __restrict__ xb,
    const unsigned short* __restrict__ wqt,
    const unsigned short* __restrict__ wkt,
    const unsigned short* __restrict__ wvt,
    const float* __restrict__ bq, const float* __restrict__ bk, const float* __restrict__ bv,
    unsigned short* __restrict__ q_ws,
    unsigned short* __restrict__ k_ws,
    unsigned short* __restrict__ v_ws) {
    int bid = blockIdx.x;
    int mt = bid / 24, c = bid % 24;
    int which = c >> 3;
    int c0 = (c & 7) * 128;
    int m0 = mt * 128;
    int tid = threadIdx.x;
    int w = tid >> 6, lane = tid & 63, g = lane >> 4, r15 = lane & 15;
    int wr = (w >> 1) * 64, wc = (w & 1) * 64;

    const unsigned short* wt = (which == 0) ? wqt : (which == 1) ? wkt : wvt;
    const float* bias = (which == 0) ? bq : (which == 1) ? bk : bv;

    const f32x4 fzero = {0.f, 0.f, 0.f, 0.f};
    f32x4 acc[4][4];
#pragma unroll
    for (int i = 0; i < 4; i++)
#pragma unroll
        for (int j = 0; j < 4; j++) acc[i][j] = fzero;

#pragma unroll
    for (int kf = 0; kf < 4; kf++) {
        s16x8 af[4], bfr[4];
#pragma unroll
        for (int mf = 0; mf < 4; mf++)
            af[mf] = *(const s16x8*)(xb + (size_t)(m0 + wr + mf * 16 + r15) * ED + kf * 32 + g * 8);
#pragma unroll
        for (int nf = 0; nf < 4; nf++)
            bfr[nf] = *(const s16x8*)(wt + (size_t)(c0 + wc + nf * 16 + r15) * ED + kf * 32 + g * 8);
#pragma unroll
        for (int mf = 0; mf < 4; mf++)
#pragma unroll
            for (int nf = 0; nf < 4; nf++)
                acc[mf][nf] = mfma16(af[mf], bfr[nf], acc[mf][nf]);
    }

    float scale = (which == 0) ? 0.08838834764831845f : 1.0f;   // 1/sqrt(128) for q only

#pragma unroll
    for (int nf = 0; nf < 4; nf++) {
        int col = c0 + wc + nf * 16 + r15;
        float bv_ = bias[col];
        int hh = col >> 7, e = col & 127;
#pragma unroll
        for (int mf = 0; mf < 4; mf++) {
#pragma unroll
            for (int rr = 0; rr < 4; rr++) {
                int row = m0 + wr + mf * 16 + g * 4 + rr;   // global token
                int bb = row >> 10, n = row & 1023;
                float val = (acc[mf][nf][rr] + bv_) * scale;
                if (which == 2)
                    v_ws[((size_t)(bb * NH + hh) * ED + e) * NN + n] = f2bf(val);   // V transposed [b][h][e][n]
                else if (which == 0)
                    q_ws[((size_t)(bb * NH + hh) * NN + n) * ED + e] = f2bf(val);
                else
                    k_ws[((size_t)(bb * NH + hh) * NN + n) * ED + e] = f2bf(val);
            }
        }
    }
}

// ---------- flash attention: R1 structure (reg-staged, 2 barriers) + fixed-max softmax ----------
__global__ __launch_bounds__(512) void attn_kernel(
    const unsigned short* __restrict__ q_ws,
    const unsigned short* __restrict__ k_ws,
    const unsigned short* __restrict__ v_ws,
    const float* __restrict__ dist,
    const float* __restrict__ mask,
    unsigned short* __restrict__ y_ws) {
    // XCD swizzle: all blocks on XCD x have b == x -> dist[b] L2-resident per XCD
    int p = blockIdx.x;
    int xcd = p & 7, j = p >> 3;
    int bh = xcd * 8 + (j >> 3);
    int qt = j & 7;
    int b = bh >> 3;
    int q0 = qt * 128;

    int tid = threadIdx.x;
    int w = tid >> 6, lane = tid & 63, g = lane >> 4, r15 = lane & 15;

    __shared__ __align__(16) unsigned short Kl[64 * 128];
    __shared__ __align__(16) unsigned short Vt[128 * 64];
    __shared__ __align__(16) unsigned short Pl[8][16 * 64];
    __shared__ float mk_s[NN];

    const unsigned short* kbase = k_ws + (size_t)bh * NN * ED;
    const unsigned short* vbase = v_ws + (size_t)bh * ED * NN;
    const float* mbase = mask + b * NN;
    const float* drow = dist + (size_t)b * NN * NN + (size_t)(q0 + w * 16 + g * 4) * NN + r15;

    // staging index decomposition (fixed per thread)
    int krow0 = tid >> 4, kseg = tid & 15;          // it=0: rows 0..31
    int vrow0 = tid >> 3, vseg = tid & 7;           // it=0: e 0..63

    // mask -> LDS once
    mk_s[tid] = mbase[tid];
    mk_s[tid + 512] = mbase[tid + 512];

    // Q fragments (registers)
    s16x8 qf[4];
    const unsigned short* qb = q_ws + ((size_t)bh * NN + q0 + w * 16 + r15) * ED;
#pragma unroll
    for (int kf = 0; kf < 4; kf++) qf[kf] = *(const s16x8*)(qb + kf * 32 + g * 8);

    const f32x4 fzero = {0.f, 0.f, 0.f, 0.f};
    f32x4 o[8];
#pragma unroll
    for (int i = 0; i < 8; i++) o[i] = fzero;
    float l_r[4] = {0.f, 0.f, 0.f, 0.f};

    // prologue: stage loads for kt=0
    s16x8 kreg[2], vreg[2];
#pragma unroll
    for (int it = 0; it < 2; ++it) {
        kreg[it] = *(const s16x8*)(kbase + (size_t)(krow0 + it * 32) * ED + kseg * 8);
        vreg[it] = *(const s16x8*)(vbase + (size_t)(vrow0 + it * 64) * NN + vseg * 8);
    }

    for (int kt = 0; kt < 16; ++kt) {
        int k0 = kt * 64;
        // write staged regs -> LDS (swizzled)
#pragma unroll
        for (int it = 0; it < 2; ++it) {
            int row = krow0 + it * 32;
            int byt = row * 256 + kseg * 16; byt ^= (row & 7) << 4;
            *(s16x8*)((char*)Kl + byt) = kreg[it];
            int e = vrow0 + it * 64;
            int vbyt = e * 128 + vseg * 16; vbyt ^= (e & 7) << 4;
            *(s16x8*)((char*)Vt + vbyt) = vreg[it];
        }
        __syncthreads();   // B1: staged tile visible to all waves

        // prefetch next K/V tile into regs (in flight across whole compute phase)
        if (kt < 15) {
            int k0n = k0 + 64;
#pragma unroll
            for (int it = 0; it < 2; ++it) {
                kreg[it] = *(const s16x8*)(kbase + (size_t)(k0n + krow0 + it * 32) * ED + kseg * 8);
                vreg[it] = *(const s16x8*)(vbase + (size_t)(vrow0 + it * 64) * NN + k0n + vseg * 8);
            }
        }

        // hoisted dist loads (16 independent; latency hides under QK^T)
        float dvv[4][4];
#pragma unroll
        for (int nf = 0; nf < 4; nf++)
#pragma unroll
            for (int rr = 0; rr < 4; rr++)
                dvv[nf][rr] = drow[(size_t)rr * NN + k0 + nf * 16];
        float mkf[4];
#pragma unroll
        for (int nf = 0; nf < 4; nf++) mkf[nf] = mk_s[k0 + nf * 16 + r15];

        // S = Q K^T  (D-layout: row=g*4+rr, col=nf*16+r15 = key)
        f32x4 s[4];
#pragma unroll
        for (int nf = 0; nf < 4; nf++) s[nf] = fzero;
#pragma unroll
        for (int kf = 0; kf < 4; kf++) {
#pragma unroll
            for (int nf = 0; nf < 4; nf++) {
                int key = nf * 16 + r15;
                int byt = (key * 256 + kf * 64 + g * 16) ^ ((key & 7) << 4);
                s16x8 kb = *(const s16x8*)((const char*)Kl + byt);
                s[nf] = mfma16(qf[kf], kb, s[nf]);
            }
        }

        // fixed-max softmax: p = exp(s + dist - 16) * mk; l accumulates lane-locally
#pragma unroll
        for (int nf = 0; nf < 4; nf++) {
#pragma unroll
            for (int rr = 0; rr < 4; rr++) {
                float pv = __expf(s[nf][rr] + dvv[nf][rr] - 16.0f) * mkf[nf];
                s[nf][rr] = pv;
                l_r[rr] += pv;
            }
        }

        // P (D-layout) -> wave-private LDS (bf16), swizzled
        unsigned short* pw = &Pl[w][0];
#pragma unroll
        for (int nf = 0; nf < 4; nf++) {
#pragma unroll
            for (int rr = 0; rr < 4; rr++) {
                int row = g * 4 + rr;
                int key = nf * 16 + r15;
                int byt = (row * 128 + key * 2) ^ ((row & 7) << 4);
                *(unsigned short*)((char*)pw + byt) = f2bf(s[nf][rr]);
            }
        }

        // O += P V  (P ordered by lgkmcnt; Vt valid since B1)
#pragma unroll
        for (int kf2 = 0; kf2 < 2; kf2++) {
            int ba = (r15 * 128 + (kf2 * 32 + g * 8) * 2) ^ ((r15 & 7) << 4);
            s16x8 pa = *(const s16x8*)((const char*)pw + ba);
#pragma unroll
            for (int nf = 0; nf < 8; nf++) {
                int e = nf * 16 + r15;
                int bb2 = (e * 128 + (kf2 * 32 + g * 8) * 2) ^ ((e & 7) << 4);
                s16x8 vb = *(const s16x8*)((const char*)Vt + bb2);
                o[nf] = mfma16(pa, vb, o[nf]);
            }
        }
        __syncthreads();   // B2: all waves done reading Kl/Vt before next overwrite
    }

    // epilogue: reduce l across the 16 key-lanes (once), normalize, write y
#pragma unroll
    for (int rr = 0; rr < 4; rr++) {
        float ps = l_r[rr];
        ps += __shfl_xor(ps, 1, 64);
        ps += __shfl_xor(ps, 2, 64);
        ps += __shfl_xor(ps, 4, 64);
        ps += __shfl_xor(ps, 8, 64);
        float inv = (ps > 0.f) ? 1.0f / ps : 0.f;
        int row_g = q0 + w * 16 + g * 4 + rr;
        size_t base = ((size_t)b * NN + row_g) * (NH * ED) + (bh & 7) * ED;
#pragma unroll
        for (int nf = 0; nf < 8; nf++)
            y_ws[base + nf * 16 + r15] = f2bf(o[nf][rr] * inv);
    }
}

// ---------- output projection: [8192,1024] @ [1024,128] + bo, * mask ----------
__global__ __launch_bounds__(256) void oproj_kernel(
    const unsigned short* __restrict__ y_ws,
    const unsigned short* __restrict__ wot,
    const float* __restrict__ bo,
    const float* __restrict__ mask,
    float* __restrict__ outp) {
    int bid = blockIdx.x;
    int mt = bid >> 1, nt = bid & 1;
    int m0 = mt * 64, c0 = nt * 64;
    int tid = threadIdx.x;
    int w = tid >> 6, lane = tid & 63, g = lane >> 4, r15 = lane & 15;

    const f32x4 fzero = {0.f, 0.f, 0.f, 0.f};
    f32x4 acc[4];
#pragma unroll
    for (int i = 0; i < 4; i++) acc[i] = fzero;

    const unsigned short* arow = y_ws + (size_t)(m0 + w * 16 + r15) * (NH * ED);
    for (int kt = 0; kt < 32; ++kt) {
        s16x8 af = *(const s16x8*)(arow + kt * 32 + g * 8);
#pragma unroll
        for (int nf = 0; nf < 4; nf++) {
            s16x8 bfr = *(const s16x8*)(wot + (size_t)(c0 + nf * 16 + r15) * (NH * ED) + kt * 32 + g * 8);
            acc[nf] = mfma16(af, bfr, acc[nf]);
        }
    }
#pragma unroll
    for (int nf = 0; nf < 4; nf++) {
        int col = c0 + nf * 16 + r15;
        float bias = bo[col];
#pragma unroll
        for (int rr = 0; rr < 4; rr++) {
            int token = m0 + w * 16 + g * 4 + rr;   // flat b*1024+n
            outp[(size_t)token * ED + col] = (acc[nf][rr] + bias) * mask[token];
        }
    }
}

extern "C" void kernel_launch(void* const* d_in, const int* in_sizes, int n_in,
                              void* d_out, int out_size, void* d_ws, size_t ws_size,
                              hipStream_t stream) {
    const float* x    = (const float*)d_in[0];
    const float* dist = (const float*)d_in[1];
    const float* mask = (const float*)d_in[2];
    const float* Wq   = (const float*)d_in[3];
    const float* bq   = (const float*)d_in[4];
    const float* Wk   = (const float*)d_in[5];
    const float* bk   = (const float*)d_in[6];
    const float* Wv   = (const float*)d_in[7];
    const float* bv   = (const float*)d_in[8];
    const float* Wo   = (const float*)d_in[9];
    const float* bo   = (const float*)d_in[10];
    float* outp = (float*)d_out;

    char* ws = (char*)d_ws;
    unsigned short* xb   = (unsigned short*)(ws);                              // 2 MB
    unsigned short* wqt  = (unsigned short*)(ws + (2u << 20));                 // 256 KB
    unsigned short* wkt  = (unsigned short*)(ws + (2u << 20) + (256u << 10));
    unsigned short* wvt  = (unsigned short*)(ws + (2u << 20) + (512u << 10));
    unsigned short* wot  = (unsigned short*)(ws + (2u << 20) + (768u << 10));
    unsigned short* q_ws = (unsigned short*)(ws + (3u << 20));                 // 16 MB
    unsigned short* k_ws = (unsigned short*)(ws + (19u << 20));                // 16 MB
    unsigned short* v_ws = (unsigned short*)(ws + (35u << 20));                // 16 MB (transposed)
    unsigned short* y_ws = (unsigned short*)(ws + (51u << 20));                // 16 MB

    prep_kernel<<<3072, 256, 0, stream>>>(x, Wq, Wk, Wv, Wo, xb, wqt, wkt, wvt, wot);
    qkv_kernel<<<1536, 256, 0, stream>>>(xb, wqt, wkt, wvt, bq, bk, bv, q_ws, k_ws, v_ws);
    attn_kernel<<<512, 512, 0, stream>>>(q_ws, k_ws, v_ws, dist, mask, y_ws);
    oproj_kernel<<<256, 256, 0, stream>>>(y_ws, wot, bo, mask, outp);
}

// Round 7
// 153.573 us; speedup vs baseline: 2.3242x; 1.0077x over previous
//
#include <hip/hip_runtime.h>
#include <hip/hip_bf16.h>

#define NH 8
#define ED 128
#define NB 8
#define NN 1024

typedef __attribute__((ext_vector_type(8))) short s16x8;
typedef __attribute__((ext_vector_type(8))) __bf16 bf16x8_t;
typedef __attribute__((ext_vector_type(4))) float f32x4;
typedef __attribute__((ext_vector_type(16))) float f32x16;
typedef __attribute__((ext_vector_type(4))) unsigned int u32x4;

static __device__ __forceinline__ unsigned short f2bf(float f) {
    union { float f; unsigned u; } v; v.f = f;
    unsigned r = v.u + 0x7fffu + ((v.u >> 16) & 1u);
    return (unsigned short)(r >> 16);
}

static __device__ __forceinline__ f32x4 mfma16(s16x8 a, s16x8 b, f32x4 c) {
    return __builtin_amdgcn_mfma_f32_16x16x32_bf16(
        __builtin_bit_cast(bf16x8_t, a), __builtin_bit_cast(bf16x8_t, b), c, 0, 0, 0);
}

static __device__ __forceinline__ f32x16 mfma32(s16x8 a, s16x8 b, f32x16 c) {
    return __builtin_amdgcn_mfma_f32_32x32x16_bf16(
        __builtin_bit_cast(bf16x8_t, a), __builtin_bit_cast(bf16x8_t, b), c, 0, 0, 0);
}

static __device__ __forceinline__ unsigned cvtpk(float lo, float hi) {
    unsigned r;
    asm("v_cvt_pk_bf16_f32 %0, %1, %2" : "=v"(r) : "v"(lo), "v"(hi));
    return r;
}

// ---------- fused prep: cvt x -> bf16, transpose 4 weight mats -> bf16 ----------
__global__ __launch_bounds__(256) void prep_kernel(
    const float* __restrict__ x,
    const float* __restrict__ Wq, const float* __restrict__ Wk,
    const float* __restrict__ Wv, const float* __restrict__ Wo,
    unsigned short* __restrict__ xb,
    unsigned short* __restrict__ wqt, unsigned short* __restrict__ wkt,
    unsigned short* __restrict__ wvt, unsigned short* __restrict__ wot) {
    int bid = blockIdx.x, tid = threadIdx.x;
    if (bid < 1024) {
        int i = bid * 256 + tid;   // 4 f32 -> 4 bf16 per thread
        float4 v = ((const float4*)x)[i];
        unsigned long long pk = (unsigned long long)f2bf(v.x)
                              | ((unsigned long long)f2bf(v.y) << 16)
                              | ((unsigned long long)f2bf(v.z) << 32)
                              | ((unsigned long long)f2bf(v.w) << 48);
        ((unsigned long long*)xb)[i] = pk;
        return;
    }
    const float* in; unsigned short* outp; int rows_in, cols_in, i;
    if (bid < 1536)      { in = Wq; outp = wqt; rows_in = 128;  cols_in = 1024; i = (bid - 1024) * 256 + tid; }
    else if (bid < 2048) { in = Wk; outp = wkt; rows_in = 128;  cols_in = 1024; i = (bid - 1536) * 256 + tid; }
    else if (bid < 2560) { in = Wv; outp = wvt; rows_in = 128;  cols_in = 1024; i = (bid - 2048) * 256 + tid; }
    else                 { in = Wo; outp = wot; rows_in = 1024; cols_in = 128;  i = (bid - 2560) * 256 + tid; }
    int c = i / rows_in;
    int r = i - c * rows_in;
    outp[i] = f2bf(in[(size_t)r * cols_in + c]);
}

// ---------- QKV projection: q/k linear [bh][n][e], v transposed [bh][e][n] ----------
__global__ __launch_bounds__(256) void qkv_kernel(
    const unsigned short* __restrict__ xb,
    const unsigned short* __restrict__ wqt,
    const unsigned short* __restrict__ wkt,
    const unsigned short* __restrict__ wvt,
    const float* __restrict__ bq, const float* __restrict__ bk, const float* __restrict__ bv,
    unsigned short* __restrict__ q_ws,
    unsigned short* __restrict__ k_ws,
    unsigned short* __restrict__ v_ws) {
    int bid = blockIdx.x;
    int mt = bid / 24, c = bid % 24;
    int which = c >> 3;
    int c0 = (c & 7) * 128;
    int m0 = mt * 128;
    int tid = threadIdx.x;
    int w = tid >> 6, lane = tid & 63, g = lane >> 4, r15 = lane & 15;
    int wr = (w >> 1) * 64, wc = (w & 1) * 64;

    const unsigned short* wt = (which == 0) ? wqt : (which == 1) ? wkt : wvt;
    const float* bias = (which == 0) ? bq : (which == 1) ? bk : bv;

    const f32x4 fzero = {0.f, 0.f, 0.f, 0.f};
    f32x4 acc[4][4];
#pragma unroll
    for (int i = 0; i < 4; i++)
#pragma unroll
        for (int j = 0; j < 4; j++) acc[i][j] = fzero;

#pragma unroll
    for (int kf = 0; kf < 4; kf++) {
        s16x8 af[4], bfr[4];
#pragma unroll
        for (int mf = 0; mf < 4; mf++)
            af[mf] = *(const s16x8*)(xb + (size_t)(m0 + wr + mf * 16 + r15) * ED + kf * 32 + g * 8);
#pragma unroll
        for (int nf = 0; nf < 4; nf++)
            bfr[nf] = *(const s16x8*)(wt + (size_t)(c0 + wc + nf * 16 + r15) * ED + kf * 32 + g * 8);
#pragma unroll
        for (int mf = 0; mf < 4; mf++)
#pragma unroll
            for (int nf = 0; nf < 4; nf++)
                acc[mf][nf] = mfma16(af[mf], bfr[nf], acc[mf][nf]);
    }

    float scale = (which == 0) ? 0.08838834764831845f : 1.0f;   // 1/sqrt(128) for q only

#pragma unroll
    for (int nf = 0; nf < 4; nf++) {
        int col = c0 + wc + nf * 16 + r15;
        float bv_ = bias[col];
        int hh = col >> 7, e = col & 127;
#pragma unroll
        for (int mf = 0; mf < 4; mf++) {
#pragma unroll
            for (int rr = 0; rr < 4; rr++) {
                int row = m0 + wr + mf * 16 + g * 4 + rr;   // global token
                int bb = row >> 10, n = row & 1023;
                float val = (acc[mf][nf][rr] + bv_) * scale;
                if (which == 2)
                    v_ws[((size_t)(bb * NH + hh) * ED + e) * NN + n] = f2bf(val);   // V transposed [b][h][e][n]
                else if (which == 0)
                    q_ws[((size_t)(bb * NH + hh) * NN + n) * ED + e] = f2bf(val);
                else
                    k_ws[((size_t)(bb * NH + hh) * NN + n) * ED + e] = f2bf(val);
            }
        }
    }
}

// ---------- flash attention: 32x32 MFMA, swapped QK^T, in-reg P, slot-packed LDS ----------
// 256 blocks: xcd=b (p&7), head=(p>>3)>>2, qt=(p>>3)&3; 8 waves x 32 q-rows = 256-row tile
__global__ __launch_bounds__(512) void attn_kernel(
    const unsigned short* __restrict__ q_ws,
    const unsigned short* __restrict__ k_ws,
    const unsigned short* __restrict__ v_ws,
    const float* __restrict__ dist,
    const float* __restrict__ mask,
    unsigned short* __restrict__ y_ws) {
    int p = blockIdx.x;
    int b = p & 7, j = p >> 3;
    int head = j >> 2, qt = j & 3;
    int bh = b * NH + head;
    int q0 = qt * 256;

    int tid = threadIdx.x;
    int w = tid >> 6, lane = tid & 63;
    int e31 = lane & 31, h = lane >> 5;
    bool h0 = (h == 0);

    // slot-packed tiles: K[estep][h][keyfrag][key31] and V[kstep][h][e] in 16B slots
    __shared__ __align__(16) unsigned short Kl[8192];   // 16 KB
    __shared__ __align__(16) unsigned short Vl[8192];   // 16 KB
    __shared__ __align__(16) float mk_s[NN];            // 4 KB

    const unsigned short* kbase = k_ws + (size_t)bh * NN * ED;
    const unsigned short* vbase = v_ws + (size_t)bh * ED * NN;

    mk_s[tid] = mask[b * NN + tid];
    mk_s[tid + 512] = mask[b * NN + tid + 512];

    int qrow = q0 + w * 32 + e31;
    const float* drow = dist + ((size_t)b * NN + qrow) * NN;

    // Q fragments (B-operand): Q[q=lane&31][e = es*16 + h*8 + j]
    s16x8 qf[8];
    const unsigned short* qb = q_ws + ((size_t)bh * NN + qrow) * ED + h * 8;
#pragma unroll
    for (int es = 0; es < 8; ++es) qf[es] = *(const s16x8*)(qb + es * 16);

    const f32x16 fz16 = {0.f,0.f,0.f,0.f,0.f,0.f,0.f,0.f,0.f,0.f,0.f,0.f,0.f,0.f,0.f,0.f};
    f32x16 o0 = fz16, o1 = fz16, o2 = fz16, o3 = fz16;
    float l_r = 0.f;

    // staging maps (precomputed): K thread->(key=tid>>3, e8=(tid&7)+8*pass)
    int k_key = tid >> 3, k_e8 = tid & 7;
    const unsigned short* kgsrc = kbase + k_key * ED + k_e8 * 8;
    int k_wb0 = ((k_e8 * 2 + (k_key >> 5)) * 32 + (k_key & 31)) * 16;
    int k_wb1 = (((k_e8 + 8) * 2 + (k_key >> 5)) * 32 + (k_key & 31)) * 16;
    // V thread->(e=tid>>2, k8=(tid&3)+4*pass)
    int v_e = tid >> 2, v_k8 = tid & 3;
    const unsigned short* vgsrc = vbase + (size_t)v_e * NN + v_k8 * 8;
    int v_wb0 = (v_k8 * 128 + v_e) * 16;
    int v_wb1 = ((v_k8 + 4) * 128 + v_e) * 16;

    // fragment-read base pointers
    const char* Kp = (const char*)Kl + h * 1024 + e31 * 16;   // + es*2048 + keyfrag*512
    const char* Vp = (const char*)Vl + h * 2048 + e31 * 16;   // + kstep*4096 + ec*512

    // prologue: stage regs for kt=0
    s16x8 kreg0 = *(const s16x8*)(kgsrc);
    s16x8 kreg1 = *(const s16x8*)(kgsrc + 64);
    s16x8 vreg0 = *(const s16x8*)(vgsrc);
    s16x8 vreg1 = *(const s16x8*)(vgsrc + 32);

    for (int kt = 0; kt < 16; ++kt) {
        int k0 = kt * 64;
        // staged regs -> LDS (slot-packed, all b128, conflict-free)
        *(s16x8*)((char*)Kl + k_wb0) = kreg0;
        *(s16x8*)((char*)Kl + k_wb1) = kreg1;
        *(s16x8*)((char*)Vl + v_wb0) = vreg0;
        *(s16x8*)((char*)Vl + v_wb1) = vreg1;
        __syncthreads();   // B1

        // prefetch next tile into regs (flies across compute)
        if (kt < 15) {
            const unsigned short* kn = kgsrc + (size_t)(kt + 1) * 64 * ED;
            kreg0 = *(const s16x8*)(kn);
            kreg1 = *(const s16x8*)(kn + 64);
            const unsigned short* vn = vgsrc + k0 + 64;
            vreg0 = *(const s16x8*)(vn);
            vreg1 = *(const s16x8*)(vn + 32);
        }

        // S^T = K Q^T : D[key][q=lane&31]; lane's scores all for q=qrow
        f32x16 sA0 = fz16, sA1 = fz16;
#pragma unroll
        for (int es = 0; es < 8; ++es) {
            s16x8 kb0 = *(const s16x8*)(Kp + es * 2048);
            s16x8 kb1 = *(const s16x8*)(Kp + es * 2048 + 512);
            sA0 = mfma32(kb0, qf[es], sA0);
            sA1 = mfma32(kb1, qf[es], sA1);
        }

        // fixed-max softmax, lane-local: key(r) = kf*32 + (r&3) + 8*(r>>2) + 4h
        float pp[32];
#pragma unroll
        for (int kf = 0; kf < 2; ++kf) {
#pragma unroll
            for (int rc = 0; rc < 4; ++rc) {
                int cb = k0 + kf * 32 + rc * 8 + 4 * h;
                f32x4 d4 = *(const f32x4*)(drow + cb);
                f32x4 m4 = *(const f32x4*)(&mk_s[cb]);
#pragma unroll
                for (int jj = 0; jj < 4; ++jj) {
                    float sv = kf ? sA1[rc * 4 + jj] : sA0[rc * 4 + jj];
                    float pv = __expf(sv + d4[jj] - 16.0f) * m4[jj];
                    pp[kf * 16 + rc * 4 + jj] = pv;
                    l_r += pv;
                }
            }
        }

        // pack P -> A-frags in-register (cvt_pk + shfl_xor(32)), then PV
#pragma unroll
        for (int kf = 0; kf < 2; ++kf) {
#pragma unroll
            for (int ks2 = 0; ks2 < 2; ++ks2) {
                const float* pb = &pp[kf * 16 + ks2 * 8];
                unsigned X0 = cvtpk(pb[0], pb[1]);
                unsigned X1 = cvtpk(pb[2], pb[3]);
                unsigned Y0 = cvtpk(pb[4], pb[5]);
                unsigned Y1 = cvtpk(pb[6], pb[7]);
                unsigned sx0 = (unsigned)__shfl_xor((int)X0, 32, 64);
                unsigned sx1 = (unsigned)__shfl_xor((int)X1, 32, 64);
                unsigned sy0 = (unsigned)__shfl_xor((int)Y0, 32, 64);
                unsigned sy1 = (unsigned)__shfl_xor((int)Y1, 32, 64);
                u32x4 pw;
                pw[0] = h0 ? X0 : sy0;
                pw[1] = h0 ? X1 : sy1;
                pw[2] = h0 ? sx0 : Y0;
                pw[3] = h0 ? sx1 : Y1;
                s16x8 pa = __builtin_bit_cast(s16x8, pw);
                int kstep = kf * 2 + ks2;
                const char* vp = Vp + kstep * 4096;
                o0 = mfma32(pa, *(const s16x8*)(vp), o0);
                o1 = mfma32(pa, *(const s16x8*)(vp + 512), o1);
                o2 = mfma32(pa, *(const s16x8*)(vp + 1024), o2);
                o3 = mfma32(pa, *(const s16x8*)(vp + 1536), o3);
            }
        }
        __syncthreads();   // B2: all reads done before next overwrite
    }

    // epilogue: l for q=lane&31 (sum both key-halves), redistribute via shfl, write y
    float lt = l_r + __shfl_xor(l_r, 32, 64);
    float inv = (lt > 0.f) ? 1.0f / lt : 0.f;
#pragma unroll
    for (int rc = 0; rc < 4; ++rc) {
#pragma unroll
        for (int jj = 0; jj < 4; ++jj) {
            int qq = jj + 8 * rc + 4 * h;           // D row = q within wave tile
            float iq = __shfl(inv, qq, 64);
            int row = q0 + w * 32 + qq;
            size_t base = ((size_t)b * NN + row) * (NH * ED) + head * ED + e31;
            y_ws[base]      = f2bf(o0[rc * 4 + jj] * iq);
            y_ws[base + 32] = f2bf(o1[rc * 4 + jj] * iq);
            y_ws[base + 64] = f2bf(o2[rc * 4 + jj] * iq);
            y_ws[base + 96] = f2bf(o3[rc * 4 + jj] * iq);
        }
    }
}

// ---------- output projection: [8192,1024] @ [1024,128] + bo, * mask ----------
__global__ __launch_bounds__(256) void oproj_kernel(
    const unsigned short* __restrict__ y_ws,
    const unsigned short* __restrict__ wot,
    const float* __restrict__ bo,
    const float* __restrict__ mask,
    float* __restrict__ outp) {
    int bid = blockIdx.x;
    int mt = bid >> 1, nt = bid & 1;
    int m0 = mt * 64, c0 = nt * 64;
    int tid = threadIdx.x;
    int w = tid >> 6, lane = tid & 63, g = lane >> 4, r15 = lane & 15;

    const f32x4 fzero = {0.f, 0.f, 0.f, 0.f};
    f32x4 acc[4];
#pragma unroll
    for (int i = 0; i < 4; i++) acc[i] = fzero;

    const unsigned short* arow = y_ws + (size_t)(m0 + w * 16 + r15) * (NH * ED);
    for (int kt = 0; kt < 32; ++kt) {
        s16x8 af = *(const s16x8*)(arow + kt * 32 + g * 8);
#pragma unroll
        for (int nf = 0; nf < 4; nf++) {
            s16x8 bfr = *(const s16x8*)(wot + (size_t)(c0 + nf * 16 + r15) * (NH * ED) + kt * 32 + g * 8);
            acc[nf] = mfma16(af, bfr, acc[nf]);
        }
    }
#pragma unroll
    for (int nf = 0; nf < 4; nf++) {
        int col = c0 + nf * 16 + r15;
        float bias = bo[col];
#pragma unroll
        for (int rr = 0; rr < 4; rr++) {
            int token = m0 + w * 16 + g * 4 + rr;   // flat b*1024+n
            outp[(size_t)token * ED + col] = (acc[nf][rr] + bias) * mask[token];
        }
    }
}

extern "C" void kernel_launch(void* const* d_in, const int* in_sizes, int n_in,
                              void* d_out, int out_size, void* d_ws, size_t ws_size,
                              hipStream_t stream) {
    const float* x    = (const float*)d_in[0];
    const float* dist = (const float*)d_in[1];
    const float* mask = (const float*)d_in[2];
    const float* Wq   = (const float*)d_in[3];
    const float* bq   = (const float*)d_in[4];
    const float* Wk   = (const float*)d_in[5];
    const float* bk   = (const float*)d_in[6];
    const float* Wv   = (const float*)d_in[7];
    const float* bv   = (const float*)d_in[8];
    const float* Wo   = (const float*)d_in[9];
    const float* bo   = (const float*)d_in[10];
    float* outp = (float*)d_out;

    char* ws = (char*)d_ws;
    unsigned short* xb   = (unsigned short*)(ws);                              // 2 MB
    unsigned short* wqt  = (unsigned short*)(ws + (2u << 20));                 // 256 KB
    unsigned short* wkt  = (unsigned short*)(ws + (2u << 20) + (256u << 10));
    unsigned short* wvt  = (unsigned short*)(ws + (2u << 20) + (512u << 10));
    unsigned short* wot  = (unsigned short*)(ws + (2u << 20) + (768u << 10));
    unsigned short* q_ws = (unsigned short*)(ws + (3u << 20));                 // 16 MB
    unsigned short* k_ws = (unsigned short*)(ws + (19u << 20));                // 16 MB
    unsigned short* v_ws = (unsigned short*)(ws + (35u << 20));                // 16 MB (transposed)
    unsigned short* y_ws = (unsigned short*)(ws + (51u << 20));                // 16 MB

    prep_kernel<<<3072, 256, 0, stream>>>(x, Wq, Wk, Wv, Wo, xb, wqt, wkt, wvt, wot);
    qkv_kernel<<<1536, 256, 0, stream>>>(xb, wqt, wkt, wvt, bq, bk, bv, q_ws, k_ws, v_ws);
    attn_kernel<<<256, 512, 0, stream>>>(q_ws, k_ws, v_ws, dist, mask, y_ws);
    oproj_kernel<<<256, 256, 0, stream>>>(y_ws, wot, bo, mask, outp);
}

// Round 8
// 135.982 us; speedup vs baseline: 2.6248x; 1.1294x over previous
//
#include <hip/hip_runtime.h>
#include <hip/hip_bf16.h>
#include <hip/hip_fp16.h>

#define NH 8
#define ED 128
#define NB 8
#define NN 1024

typedef __attribute__((ext_vector_type(8))) short s16x8;
typedef __attribute__((ext_vector_type(8))) __bf16 bf16x8_t;
typedef __attribute__((ext_vector_type(4))) float f32x4;
typedef __attribute__((ext_vector_type(16))) float f32x16;
typedef __attribute__((ext_vector_type(4))) unsigned int u32x4;

static __device__ __forceinline__ unsigned short f2bf(float f) {
    union { float f; unsigned u; } v; v.f = f;
    unsigned r = v.u + 0x7fffu + ((v.u >> 16) & 1u);
    return (unsigned short)(r >> 16);
}

static __device__ __forceinline__ f32x4 mfma16(s16x8 a, s16x8 b, f32x4 c) {
    return __builtin_amdgcn_mfma_f32_16x16x32_bf16(
        __builtin_bit_cast(bf16x8_t, a), __builtin_bit_cast(bf16x8_t, b), c, 0, 0, 0);
}

static __device__ __forceinline__ f32x16 mfma32(s16x8 a, s16x8 b, f32x16 c) {
    return __builtin_amdgcn_mfma_f32_32x32x16_bf16(
        __builtin_bit_cast(bf16x8_t, a), __builtin_bit_cast(bf16x8_t, b), c, 0, 0, 0);
}

static __device__ __forceinline__ unsigned cvtpk(float lo, float hi) {
    unsigned r;
    asm("v_cvt_pk_bf16_f32 %0, %1, %2" : "=v"(r) : "v"(lo), "v"(hi));
    return r;
}

// async global->LDS, 16B per lane; LDS dest is wave-uniform base (+ lane*16 by HW)
static __device__ __forceinline__ void gll16(const void* g, void* l) {
    __builtin_amdgcn_global_load_lds((const __attribute__((address_space(1))) void*)g,
                                     (__attribute__((address_space(3))) void*)l, 16, 0, 0);
}

// ---------- fused prep: cvt x -> bf16, transpose 4 weight mats -> bf16 ----------
__global__ __launch_bounds__(256) void prep_kernel(
    const float* __restrict__ x,
    const float* __restrict__ Wq, const float* __restrict__ Wk,
    const float* __restrict__ Wv, const float* __restrict__ Wo,
    unsigned short* __restrict__ xb,
    unsigned short* __restrict__ wqt, unsigned short* __restrict__ wkt,
    unsigned short* __restrict__ wvt, unsigned short* __restrict__ wot) {
    int bid = blockIdx.x, tid = threadIdx.x;
    if (bid < 1024) {
        int i = bid * 256 + tid;
        float4 v = ((const float4*)x)[i];
        unsigned long long pk = (unsigned long long)f2bf(v.x)
                              | ((unsigned long long)f2bf(v.y) << 16)
                              | ((unsigned long long)f2bf(v.z) << 32)
                              | ((unsigned long long)f2bf(v.w) << 48);
        ((unsigned long long*)xb)[i] = pk;
        return;
    }
    const float* in; unsigned short* outp; int rows_in, cols_in, i;
    if (bid < 1536)      { in = Wq; outp = wqt; rows_in = 128;  cols_in = 1024; i = (bid - 1024) * 256 + tid; }
    else if (bid < 2048) { in = Wk; outp = wkt; rows_in = 128;  cols_in = 1024; i = (bid - 1536) * 256 + tid; }
    else if (bid < 2560) { in = Wv; outp = wvt; rows_in = 128;  cols_in = 1024; i = (bid - 2048) * 256 + tid; }
    else                 { in = Wo; outp = wot; rows_in = 1024; cols_in = 128;  i = (bid - 2560) * 256 + tid; }
    int c = i / rows_in;
    int r = i - c * rows_in;
    outp[i] = f2bf(in[(size_t)r * cols_in + c]);
}

// ---------- prep dist: f32 dist + mask -> f16 swizzled per-(b,qt,kt,c,tid) chunks ----------
// chunk value u (0..7) for lane tid: i = c*8+u; col = (i>>4)*32 + ((i>>2)&3)*8 + 4h + (i&3)
__global__ __launch_bounds__(256) void prep_dist_kernel(
    const float* __restrict__ dist,
    const float* __restrict__ mask,
    unsigned short* __restrict__ dswz) {
    int bid = blockIdx.x;                 // (((b*8+qt)*16 + kt)*4 + c)
    int c = bid & 3;
    int t = bid >> 2;
    int kt = t & 15; t >>= 4;
    int qt = t & 7;
    int b = t >> 3;
    int tid = threadIdx.x;
    int h = (tid >> 5) & 1;
    int row = qt * 128 + (tid >> 6) * 32 + (tid & 31);
    int colbase = kt * 64 + (c >> 1) * 32 + (c & 1) * 16 + 4 * h;

    const float* dr = dist + ((size_t)b * NN + row) * NN;
    const float* mr = mask + (size_t)b * NN;
    f32x4 dA = *(const f32x4*)(dr + colbase);
    f32x4 dB = *(const f32x4*)(dr + colbase + 8);
    f32x4 mA = *(const f32x4*)(mr + colbase);
    f32x4 mB = *(const f32x4*)(mr + colbase + 8);

    unsigned short o[8];
#pragma unroll
    for (int jj = 0; jj < 4; ++jj) {
        o[jj]     = (mA[jj] == 0.0f) ? (unsigned short)0xFBFF   // -65504: exp underflows to 0
                                     : __half_as_ushort(__float2half_rn(dA[jj]));
        o[4 + jj] = (mB[jj] == 0.0f) ? (unsigned short)0xFBFF
                                     : __half_as_ushort(__float2half_rn(dB[jj]));
    }
    u32x4 pk;
    pk[0] = (unsigned)o[0] | ((unsigned)o[1] << 16);
    pk[1] = (unsigned)o[2] | ((unsigned)o[3] << 16);
    pk[2] = (unsigned)o[4] | ((unsigned)o[5] << 16);
    pk[3] = (unsigned)o[6] | ((unsigned)o[7] << 16);
    *(u32x4*)(dswz + ((size_t)bid * 256 + tid) * 8) = pk;
}

// ---------- QKV projection: q linear; K/V written in gll slot layout (16KB tiles) ----------
__global__ __launch_bounds__(256) void qkv_kernel(
    const unsigned short* __restrict__ xb,
    const unsigned short* __restrict__ wqt,
    const unsigned short* __restrict__ wkt,
    const unsigned short* __restrict__ wvt,
    const float* __restrict__ bq, const float* __restrict__ bk, const float* __restrict__ bv,
    unsigned short* __restrict__ q_ws,
    unsigned short* __restrict__ k_ws,
    unsigned short* __restrict__ v_ws) {
    int bid = blockIdx.x;
    int mt = bid / 24, c = bid % 24;
    int which = c >> 3;
    int c0 = (c & 7) * 128;
    int m0 = mt * 128;
    int tid = threadIdx.x;
    int w = tid >> 6, lane = tid & 63, g = lane >> 4, r15 = lane & 15;
    int wr = (w >> 1) * 64, wc = (w & 1) * 64;

    const unsigned short* wt = (which == 0) ? wqt : (which == 1) ? wkt : wvt;
    const float* bias = (which == 0) ? bq : (which == 1) ? bk : bv;

    const f32x4 fzero = {0.f, 0.f, 0.f, 0.f};
    f32x4 acc[4][4];
#pragma unroll
    for (int i = 0; i < 4; i++)
#pragma unroll
        for (int j = 0; j < 4; j++) acc[i][j] = fzero;

#pragma unroll
    for (int kf = 0; kf < 4; kf++) {
        s16x8 af[4], bfr[4];
#pragma unroll
        for (int mf = 0; mf < 4; mf++)
            af[mf] = *(const s16x8*)(xb + (size_t)(m0 + wr + mf * 16 + r15) * ED + kf * 32 + g * 8);
#pragma unroll
        for (int nf = 0; nf < 4; nf++)
            bfr[nf] = *(const s16x8*)(wt + (size_t)(c0 + wc + nf * 16 + r15) * ED + kf * 32 + g * 8);
#pragma unroll
        for (int mf = 0; mf < 4; mf++)
#pragma unroll
            for (int nf = 0; nf < 4; nf++)
                acc[mf][nf] = mfma16(af[mf], bfr[nf], acc[mf][nf]);
    }

    float scale = (which == 0) ? 0.08838834764831845f : 1.0f;   // 1/sqrt(128) for q only

#pragma unroll
    for (int nf = 0; nf < 4; nf++) {
        int col = c0 + wc + nf * 16 + r15;
        float bv_ = bias[col];
        int hh = col >> 7, e = col & 127;
#pragma unroll
        for (int mf = 0; mf < 4; mf++) {
#pragma unroll
            for (int rr = 0; rr < 4; rr++) {
                int row = m0 + wr + mf * 16 + g * 4 + rr;   // global token
                int bb = row >> 10, n = row & 1023;
                int bh = bb * NH + hh;
                float val = (acc[mf][nf][rr] + bv_) * scale;
                if (which == 0) {
                    q_ws[((size_t)bh * NN + n) * ED + e] = f2bf(val);
                } else if (which == 1) {
                    // K slot: [es=e>>4][h=(e>>3)&1][kf=k>>5][k&31], elem j=e&7
                    int ktl = n >> 6, k = n & 63;
                    int slot = (e >> 4) * 128 + ((e >> 3) & 1) * 64 + (k >> 5) * 32 + (k & 31);
                    k_ws[(size_t)(bh * 16 + ktl) * 8192 + slot * 8 + (e & 7)] = f2bf(val);
                } else {
                    // V slot: [kstep=k>>4][hk=(k>>3)&1][ec=e>>5][e&31], elem j=k&7
                    int ktl = n >> 6, k = n & 63;
                    int slot = (k >> 4) * 256 + ((k >> 3) & 1) * 128 + (e >> 5) * 32 + (e & 31);
                    v_ws[(size_t)(bh * 16 + ktl) * 8192 + slot * 8 + (k & 7)] = f2bf(val);
                }
            }
        }
    }
}

// ---------- flash attention: 32x32 swapped, gll dbuf 1-barrier, swizzled f16 dist ----------
// 512 blocks x 256 thr (4 waves x 32 q-rows = 128-row tile); b = blockIdx&7 (XCD-pinned)
__global__ __launch_bounds__(256) void attn_kernel(
    const unsigned short* __restrict__ q_ws,
    const unsigned short* __restrict__ k_ws,
    const unsigned short* __restrict__ v_ws,
    const unsigned short* __restrict__ dswz,
    unsigned short* __restrict__ y_ws) {
    int p = blockIdx.x;
    int b = p & 7, r = p >> 3;
    int head = r >> 3, qt = r & 7;
    int bh = b * NH + head;
    int q0 = qt * 128;

    int tid = threadIdx.x;
    int w = tid >> 6, lane = tid & 63;
    int e31 = lane & 31, h = lane >> 5;
    bool h0 = (h == 0);

    __shared__ __align__(16) unsigned short Kl[2][8192];   // 32 KB dbuf
    __shared__ __align__(16) unsigned short Vl[2][8192];   // 32 KB dbuf

    const char* kg = (const char*)k_ws + (size_t)bh * 16 * 16384;
    const char* vg = (const char*)v_ws + (size_t)bh * 16 * 16384;
    const char* dq = (const char*)dswz + ((size_t)(b * 8 + qt) << 18);   // 256KB per (b,qt)

    int qrow = q0 + w * 32 + e31;
    s16x8 qf[8];
    const unsigned short* qb = q_ws + ((size_t)bh * NN + qrow) * ED + h * 8;
#pragma unroll
    for (int es = 0; es < 8; ++es) qf[es] = *(const s16x8*)(qb + es * 16);

    const f32x16 fz16 = {0.f,0.f,0.f,0.f,0.f,0.f,0.f,0.f,0.f,0.f,0.f,0.f,0.f,0.f,0.f,0.f};
    f32x16 o0 = fz16, o1 = fz16, o2 = fz16, o3 = fz16;
    float l_r = 0.f;

    // prologue: stage tile 0 into buf 0
#pragma unroll
    for (int pass = 0; pass < 4; ++pass) {
        gll16(kg + (pass * 256 + tid) * 16, (char*)&Kl[0][0] + pass * 4096 + w * 1024);
        gll16(vg + (pass * 256 + tid) * 16, (char*)&Vl[0][0] + pass * 4096 + w * 1024);
    }
    __syncthreads();

    for (int kt = 0; kt < 16; ++kt) {
        int cur = kt & 1;
        // issue next tile into nxt (full-iteration slack; drained by end-of-iter barrier)
        if (kt < 15) {
            const char* kn = kg + (size_t)(kt + 1) * 16384;
            const char* vn = vg + (size_t)(kt + 1) * 16384;
            char* kd = (char*)&Kl[cur ^ 1][0] + w * 1024;
            char* vd = (char*)&Vl[cur ^ 1][0] + w * 1024;
#pragma unroll
            for (int pass = 0; pass < 4; ++pass) {
                gll16(kn + (pass * 256 + tid) * 16, kd + pass * 4096);
                gll16(vn + (pass * 256 + tid) * 16, vd + pass * 4096);
            }
        }

        // coalesced f16 dist+mask chunks (L2-resident; consumed after QK^T)
        u32x4 dch[4];
#pragma unroll
        for (int c = 0; c < 4; ++c)
            dch[c] = *(const u32x4*)(dq + ((size_t)(kt * 4 + c) * 256 + tid) * 16);

        // S^T = K Q^T : lane holds all 32 (of 64, split by h) scores for q = qrow
        const char* Kp = (const char*)&Kl[cur][0] + h * 1024 + e31 * 16;
        f32x16 sA0 = fz16, sA1 = fz16;
#pragma unroll
        for (int es = 0; es < 8; ++es) {
            s16x8 kb0 = *(const s16x8*)(Kp + es * 2048);
            s16x8 kb1 = *(const s16x8*)(Kp + es * 2048 + 512);
            sA0 = mfma32(kb0, qf[es], sA0);
            sA1 = mfma32(kb1, qf[es], sA1);
        }

        // fixed-max softmax with mask folded into dist (masked -> -65504 -> p=0)
        float pp[32];
#pragma unroll
        for (int c = 0; c < 4; ++c) {
#pragma unroll
            for (int u = 0; u < 8; ++u) {
                int i = c * 8 + u;
                unsigned wv = dch[c][u >> 1];
                float dv = __half2float(__ushort_as_half(
                    (unsigned short)((u & 1) ? (wv >> 16) : (wv & 0xffff))));
                float sv = (i < 16) ? sA0[i] : sA1[i - 16];
                float pv = __expf(sv + dv - 16.0f);
                pp[i] = pv;
                l_r += pv;
            }
        }

        // pack P -> A-frags in-register (cvt_pk + shfl_xor(32)), then PV
        const char* Vp = (const char*)&Vl[cur][0] + h * 2048 + e31 * 16;
#pragma unroll
        for (int kf = 0; kf < 2; ++kf) {
#pragma unroll
            for (int ks2 = 0; ks2 < 2; ++ks2) {
                const float* pb = &pp[kf * 16 + ks2 * 8];
                unsigned X0 = cvtpk(pb[0], pb[1]);
                unsigned X1 = cvtpk(pb[2], pb[3]);
                unsigned Y0 = cvtpk(pb[4], pb[5]);
                unsigned Y1 = cvtpk(pb[6], pb[7]);
                unsigned sx0 = (unsigned)__shfl_xor((int)X0, 32, 64);
                unsigned sx1 = (unsigned)__shfl_xor((int)X1, 32, 64);
                unsigned sy0 = (unsigned)__shfl_xor((int)Y0, 32, 64);
                unsigned sy1 = (unsigned)__shfl_xor((int)Y1, 32, 64);
                u32x4 pw;
                pw[0] = h0 ? X0 : sy0;
                pw[1] = h0 ? X1 : sy1;
                pw[2] = h0 ? sx0 : Y0;
                pw[3] = h0 ? sx1 : Y1;
                s16x8 pa = __builtin_bit_cast(s16x8, pw);
                int kstep = kf * 2 + ks2;
                const char* vp = Vp + kstep * 4096;
                o0 = mfma32(pa, *(const s16x8*)(vp), o0);
                o1 = mfma32(pa, *(const s16x8*)(vp + 512), o1);
                o2 = mfma32(pa, *(const s16x8*)(vp + 1024), o2);
                o3 = mfma32(pa, *(const s16x8*)(vp + 1536), o3);
            }
        }
        __syncthreads();   // one barrier/iter: drains gll(nxt) + guards cur reuse
    }

    // epilogue: merge l across h-halves, distribute inverse, write y
    float lt = l_r + __shfl_xor(l_r, 32, 64);
    float inv = (lt > 0.f) ? 1.0f / lt : 0.f;
#pragma unroll
    for (int rc = 0; rc < 4; ++rc) {
#pragma unroll
        for (int jj = 0; jj < 4; ++jj) {
            int qq = jj + 8 * rc + 4 * h;
            float iq = __shfl(inv, qq, 64);
            int row = q0 + w * 32 + qq;
            size_t base = ((size_t)b * NN + row) * (NH * ED) + head * ED + e31;
            y_ws[base]      = f2bf(o0[rc * 4 + jj] * iq);
            y_ws[base + 32] = f2bf(o1[rc * 4 + jj] * iq);
            y_ws[base + 64] = f2bf(o2[rc * 4 + jj] * iq);
            y_ws[base + 96] = f2bf(o3[rc * 4 + jj] * iq);
        }
    }
}

// ---------- output projection: [8192,1024] @ [1024,128] + bo, * mask ----------
__global__ __launch_bounds__(256) void oproj_kernel(
    const unsigned short* __restrict__ y_ws,
    const unsigned short* __restrict__ wot,
    const float* __restrict__ bo,
    const float* __restrict__ mask,
    float* __restrict__ outp) {
    int bid = blockIdx.x;
    int mt = bid >> 1, nt = bid & 1;
    int m0 = mt * 64, c0 = nt * 64;
    int tid = threadIdx.x;
    int w = tid >> 6, lane = tid & 63, g = lane >> 4, r15 = lane & 15;

    const f32x4 fzero = {0.f, 0.f, 0.f, 0.f};
    f32x4 acc[4];
#pragma unroll
    for (int i = 0; i < 4; i++) acc[i] = fzero;

    const unsigned short* arow = y_ws + (size_t)(m0 + w * 16 + r15) * (NH * ED);
    for (int kt = 0; kt < 32; ++kt) {
        s16x8 af = *(const s16x8*)(arow + kt * 32 + g * 8);
#pragma unroll
        for (int nf = 0; nf < 4; nf++) {
            s16x8 bfr = *(const s16x8*)(wot + (size_t)(c0 + nf * 16 + r15) * (NH * ED) + kt * 32 + g * 8);
            acc[nf] = mfma16(af, bfr, acc[nf]);
        }
    }
#pragma unroll
    for (int nf = 0; nf < 4; nf++) {
        int col = c0 + nf * 16 + r15;
        float bias = bo[col];
#pragma unroll
        for (int rr = 0; rr < 4; rr++) {
            int token = m0 + w * 16 + g * 4 + rr;
            outp[(size_t)token * ED + col] = (acc[nf][rr] + bias) * mask[token];
        }
    }
}

extern "C" void kernel_launch(void* const* d_in, const int* in_sizes, int n_in,
                              void* d_out, int out_size, void* d_ws, size_t ws_size,
                              hipStream_t stream) {
    const float* x    = (const float*)d_in[0];
    const float* dist = (const float*)d_in[1];
    const float* mask = (const float*)d_in[2];
    const float* Wq   = (const float*)d_in[3];
    const float* bq   = (const float*)d_in[4];
    const float* Wk   = (const float*)d_in[5];
    const float* bk   = (const float*)d_in[6];
    const float* Wv   = (const float*)d_in[7];
    const float* bv   = (const float*)d_in[8];
    const float* Wo   = (const float*)d_in[9];
    const float* bo   = (const float*)d_in[10];
    float* outp = (float*)d_out;

    char* ws = (char*)d_ws;
    unsigned short* xb   = (unsigned short*)(ws);                              // 2 MB
    unsigned short* wqt  = (unsigned short*)(ws + (2u << 20));                 // 256 KB
    unsigned short* wkt  = (unsigned short*)(ws + (2u << 20) + (256u << 10));
    unsigned short* wvt  = (unsigned short*)(ws + (2u << 20) + (512u << 10));
    unsigned short* wot  = (unsigned short*)(ws + (2u << 20) + (768u << 10));
    unsigned short* q_ws = (unsigned short*)(ws + (3u << 20));                 // 16 MB
    unsigned short* k_ws = (unsigned short*)(ws + (19u << 20));                // 16 MB (slot tiles)
    unsigned short* v_ws = (unsigned short*)(ws + (35u << 20));                // 16 MB (slot tiles)
    unsigned short* y_ws = (unsigned short*)(ws + (51u << 20));                // 16 MB
    unsigned short* dswz = (unsigned short*)(ws + (67u << 20));                // 16.78 MB f16 dist+mask

    prep_kernel<<<3072, 256, 0, stream>>>(x, Wq, Wk, Wv, Wo, xb, wqt, wkt, wvt, wot);
    prep_dist_kernel<<<4096, 256, 0, stream>>>(dist, mask, dswz);
    qkv_kernel<<<1536, 256, 0, stream>>>(xb, wqt, wkt, wvt, bq, bk, bv, q_ws, k_ws, v_ws);
    attn_kernel<<<512, 256, 0, stream>>>(q_ws, k_ws, v_ws, dswz, y_ws);
    oproj_kernel<<<256, 256, 0, stream>>>(y_ws, wot, bo, mask, outp);
}